// Round 10
// baseline (309.687 us; speedup 1.0000x reference)
//
#include <hip/hip_runtime.h>

// Problem constants
#define B_   2
#define S_   2048
#define D_   2048
#define NQ_  32
#define NKV_ 8
#define HD_  64
// g = NQ/NKV = 4

typedef unsigned short u16;
typedef __bf16 bf16x8 __attribute__((ext_vector_type(8)));
typedef __bf16 bf16x4 __attribute__((ext_vector_type(4)));
typedef short  s16x4  __attribute__((ext_vector_type(4)));
typedef float  f32x4  __attribute__((ext_vector_type(4)));

#define GLB __attribute__((address_space(1)))
#define LDS __attribute__((address_space(3)))

__device__ inline u16 f2b(float f){
  union { float f; unsigned u; } v; v.f = f;
  unsigned r = (v.u + 0x7fffu + ((v.u >> 16) & 1u)) >> 16;
  return (u16)r;
}
__device__ inline float b2f(u16 b){
  union { unsigned u; float f; } v; v.u = ((unsigned)b) << 16;
  return v.f;
}

// 16x16x16 bf16 MFMA (v_mfma_f32_16x16x16_bf16 on gfx950).
// NOTE: no __has_builtin guard — it checks the HOST target in HIP and lies.
__device__ inline f32x4 mfma16(bf16x4 a, bf16x4 b, f32x4 c){
  union U { bf16x4 b; s16x4 s; };
  U ua, ub; ua.b = a; ub.b = b;
  return __builtin_amdgcn_mfma_f32_16x16x16bf16_1k(ua.s, ub.s, c, 0, 0, 0);
}

// truncation-pack 4 fp32 -> bf16x4 (softmax normalization cancels the
// common-mode 2^-9 truncation bias)
__device__ inline bf16x4 pack4(float p0, float p1, float p2, float p3){
  union { float f; unsigned u; } a, b, c, d;
  a.f = p0; b.f = p1; c.f = p2; d.f = p3;
  union { uint2 u; bf16x4 v; } r;
  r.u.x = (a.u >> 16) | (b.u & 0xffff0000u);
  r.u.y = (c.u >> 16) | (d.u & 0xffff0000u);
  return r.v;
}

// ---------------- fp32 -> bf16 convert, all 5 regions in one launch ---------
__global__ void k_f2b_all(const float* __restrict__ x,  const float* __restrict__ wq,
                          const float* __restrict__ wk, const float* __restrict__ wv,
                          const float* __restrict__ wo,
                          u16* __restrict__ xb, u16* __restrict__ wqkvb, u16* __restrict__ wob){
  int i = blockIdx.x * blockDim.x + threadIdx.x;   // < 4718592
  const float* src; u16* dst; int off;
  if (i < 2097152)      { src = x;  dst = xb;                  off = i; }
  else if (i < 3145728) { src = wq; dst = wqkvb;               off = i - 2097152; }
  else if (i < 3407872) { src = wk; dst = wqkvb + 2048*2048;   off = i - 3145728; }
  else if (i < 3670016) { src = wv; dst = wqkvb + 2560*2048;   off = i - 3407872; }
  else                  { src = wo; dst = wob;                 off = i - 3670016; }
  float4 f = ((const float4*)src)[off];
  uint2 pk;
  pk.x = (unsigned)f2b(f.x) | ((unsigned)f2b(f.y) << 16);
  pk.y = (unsigned)f2b(f.z) | ((unsigned)f2b(f.w) << 16);
  ((uint2*)dst)[off] = pk;
}

// ======================= shared GEMM core (BK=64, swizzled) =================
// LDS: chunk s of row r holds GLOBAL chunk s^(r&7); DMA permutes the global
// column per lane (LDS side stays the required contiguous lane*16B pattern).
#define GEMM_CORE(K)                                                           \
  __shared__ __align__(16) u16 As[128*64];                                     \
  __shared__ __align__(16) u16 Bs[128*64];                                     \
  const int tid  = threadIdx.x;                                               \
  const int lane = tid & 63;                                                  \
  const int wave = tid >> 6;                                                  \
  const int wm = wave >> 1, wn = wave & 1;                                    \
  const int quad = lane >> 4, l16 = lane & 15;                                \
  const u16* Ab = A  + (size_t)blockIdx.y * 128 * (K);                        \
  const u16* Bb = Bm + (size_t)blockIdx.x * 128 * (K);                        \
  f32x4 acc[4][4];                                                            \
  for (int i = 0; i < 4; i++)                                                 \
    for (int j = 0; j < 4; j++) acc[i][j] = (f32x4){0.f, 0.f, 0.f, 0.f};      \
  const int R0 = wave * 32;                                                   \
  const int lr = lane >> 3;                                                   \
  const int gc = ((lane & 7) ^ lr) * 8;                                       \
  const int sk = l16 & 7;                                                     \
  for (int k0 = 0; k0 < (K); k0 += 64){                                       \
    __syncthreads();                                                          \
    _Pragma("unroll")                                                         \
    for (int m = 0; m < 4; m++){                                              \
      const u16* ga = Ab + (size_t)(R0 + m*8 + lr) * (K) + k0 + gc;           \
      const u16* gb = Bb + (size_t)(R0 + m*8 + lr) * (K) + k0 + gc;           \
      __builtin_amdgcn_global_load_lds((const GLB void*)ga, (LDS void*)&As[(R0 + m*8)*64], 16, 0, 0); \
      __builtin_amdgcn_global_load_lds((const GLB void*)gb, (LDS void*)&Bs[(R0 + m*8)*64], 16, 0, 0); \
    }                                                                          \
    __syncthreads();                                                          \
    bf16x8 af[4][2], bfr[4][2];                                               \
    _Pragma("unroll")                                                         \
    for (int i = 0; i < 4; i++)                                               \
      _Pragma("unroll")                                                       \
      for (int h = 0; h < 2; h++)                                             \
        af[i][h]  = *(const bf16x8*)&As[(wm*64 + i*16 + l16)*64 + (((h*4 + quad) ^ sk)*8)]; \
    _Pragma("unroll")                                                         \
    for (int j = 0; j < 4; j++)                                               \
      _Pragma("unroll")                                                       \
      for (int h = 0; h < 2; h++)                                             \
        bfr[j][h] = *(const bf16x8*)&Bs[(wn*64 + j*16 + l16)*64 + (((h*4 + quad) ^ sk)*8)]; \
    _Pragma("unroll")                                                         \
    for (int i = 0; i < 4; i++)                                               \
      _Pragma("unroll")                                                       \
      for (int j = 0; j < 4; j++){                                            \
        acc[i][j] = __builtin_amdgcn_mfma_f32_16x16x32_bf16(af[i][0], bfr[j][0], acc[i][j], 0, 0, 0); \
        acc[i][j] = __builtin_amdgcn_mfma_f32_16x16x32_bf16(af[i][1], bfr[j][1], acc[i][j], 0, 0, 0); \
      }                                                                        \
  }

// ---------------- fused QKV GEMM + RoPE + scatter ----------------
#define QSCALE 0.18033688011112042f
__global__ __launch_bounds__(256, 3) void k_gemm_qkv(const u16* __restrict__ A,
                                                     const u16* __restrict__ Bm,
                                                     u16* __restrict__ qT,
                                                     u16* __restrict__ kT,
                                                     u16* __restrict__ vT){
  GEMM_CORE(2048)

  // ---- fused epilogue ----
  const int cb = blockIdx.x*128 + wn*64;   // wave's 64-col span = one head

  if (cb < 2560){
    const bool isq = (cb < 2048);
    const int hh   = (isq ? cb : (cb - 2048)) >> 6;
    const int NH   = isq ? NQ_ : NKV_;
    u16* base      = isq ? qT : kT;
    const float sc = isq ? QSCALE : 1.0f;
    #pragma unroll
    for (int j = 0; j < 2; j++){
      const int d2 = j*16 + l16;
      const float invf = __expf(-(float)d2 * (9.210340371976184f / 32.0f));
      #pragma unroll
      for (int i = 0; i < 4; i++){
        const int row0 = blockIdx.y*128 + wm*64 + i*16 + quad*4;
        #pragma unroll
        for (int r = 0; r < 4; r++){
          const int row = row0 + r;
          const int s = row & (S_ - 1), b = row >> 11;
          float ang = (float)s * invf;
          float sn = __sinf(ang), cs = __cosf(ang);   // hw v_sin/v_cos
          const float x1 = acc[i][j][r] * sc, x2 = acc[i][j+2][r] * sc;
          u16* drow = base + ((size_t)(b*NH + hh) * S_ + s) * 64;
          drow[d2]      = f2b(x1*cs - x2*sn);
          drow[d2 + 32] = f2b(x2*cs + x1*sn);
        }
      }
    }
  } else {
    const int fbase = cb - 2560;
    #pragma unroll
    for (int j = 0; j < 4; j++){
      const int f = fbase + j*16 + l16;
      const int kvh = f >> 6, d = f & 63;
      #pragma unroll
      for (int i = 0; i < 4; i++){
        const int row0 = blockIdx.y*128 + wm*64 + i*16 + quad*4;
        const int s0 = row0 & (S_ - 1), b = row0 >> 11;
        uint2 pk;
        pk.x = (unsigned)f2b(acc[i][j][0]) | ((unsigned)f2b(acc[i][j][1]) << 16);
        pk.y = (unsigned)f2b(acc[i][j][2]) | ((unsigned)f2b(acc[i][j][3]) << 16);
        *(uint2*)(vT + ((size_t)(b*NKV_ + kvh) * 64 + d) * S_ + s0) = pk;
      }
    }
  }
}

// ---------------- out-proj GEMM: fp32 epilogue ----------------
__global__ __launch_bounds__(256, 3) void k_gemm_bt(const u16* __restrict__ A,
                                                    const u16* __restrict__ Bm,
                                                    float* __restrict__ C,
                                                    int N){
  GEMM_CORE(2048)
  for (int i = 0; i < 4; i++){
    int row0 = blockIdx.y*128 + wm*64 + i*16 + quad*4;
    for (int j = 0; j < 4; j++){
      int col = blockIdx.x*128 + wn*64 + j*16 + l16;
      for (int r = 0; r < 4; r++)
        C[(size_t)(row0 + r) * N + col] = acc[i][j][r];
    }
  }
}

// ---------------- flash attention: split-K halves, uniform 17 chunks --------
// Fixed-max softmax => partial (O,l) over disjoint key ranges simply ADD.
// Tile T (128 queries) needs chunks [0, 2T+2); split at T+1 into two equal
// halves. Block (b,kvh,hq,p,half) processes: half A: half0(tile p) then
// half1(tile 15-p); half B: half1(tile p) then half0(tile 15-p) — always
// (p+1) + (16-p) = 17 chunks. 1024 blocks, 4/CU, perfectly uniform.
// half0 partials -> (P1,l1), half1 -> (P2,l2); k_combine adds+normalizes.
// kvh = bid&7 -> KV-head XCD locality. 128q tile: each wave owns 2 strips,
// K/V LDS reads shared across strips.
__global__ __launch_bounds__(256) void k_attn(const u16* __restrict__ qT,
                                              const u16* __restrict__ kT,
                                              const u16* __restrict__ vT,
                                              u16* __restrict__ P1,
                                              u16* __restrict__ P2,
                                              float* __restrict__ l1,
                                              float* __restrict__ l2){
  __shared__ __align__(16) u16 Ks[2][64*64];
  __shared__ __align__(16) u16 Vs[2][64*64];

  const int bid  = blockIdx.x;
  const int kvh  = bid & 7;
  const int b    = (bid >> 3) & 1;
  const int hq   = (bid >> 4) & 3;
  const int p    = (bid >> 6) & 7;
  const int half = bid >> 9;             // 0: A, 1: B
  const int h    = kvh*4 + hq;
  const int lane = threadIdx.x & 63, w = threadIdx.x >> 6;
  const int quad = lane >> 4, l16 = lane & 15;

  const u16* Qh = qT + (size_t)(b*NQ_ + h)    * S_ * 64;
  const u16* Kh = kT + (size_t)(b*NKV_ + kvh) * S_ * 64;
  const u16* Vh = vT + (size_t)(b*NKV_ + kvh) * 64 * S_;

  const int rr = lane >> 3;
  const int gg = (lane & 7) ^ rr;
  const int R  = w * 16;

  auto stage = [&](int c, int buf){
    const int kb = c * 64;
    const u16* gk0 = Kh + (size_t)(kb + R + rr)     * 64 + gg*8;
    const u16* gk1 = Kh + (size_t)(kb + R + 8 + rr) * 64 + gg*8;
    const u16* gv0 = Vh + (size_t)(R + rr)     * S_ + kb + gg*8;
    const u16* gv1 = Vh + (size_t)(R + 8 + rr) * S_ + kb + gg*8;
    __builtin_amdgcn_global_load_lds((const GLB void*)gk0, (LDS void*)&Ks[buf][R*64],     16, 0, 0);
    __builtin_amdgcn_global_load_lds((const GLB void*)gk1, (LDS void*)&Ks[buf][(R+8)*64], 16, 0, 0);
    __builtin_amdgcn_global_load_lds((const GLB void*)gv0, (LDS void*)&Vs[buf][R*64],     16, 0, 0);
    __builtin_amdgcn_global_load_lds((const GLB void*)gv1, (LDS void*)&Vs[buf][(R+8)*64], 16, 0, 0);
  };

  // hoisted chunk-invariant swizzled offsets (u16 units)
  const int sw    = l16 & 7;
  const int koff0 = ((quad    ) ^ sw) * 8;
  const int koff1 = ((quad + 4) ^ sw) * 8;
  int voff[4];
  #pragma unroll
  for (int t = 0; t < 4; t++)
    voff[t] = (((2*t + (quad >> 1)) ^ sw) * 8) + (quad & 1)*4;

  for (int ph = 0; ph < 2; ph++){
    int tile, c0, c1, slot;
    if (ph == 0){ tile = p;
      if (half == 0){ c0 = 0;      c1 = p + 1;     slot = 0; }
      else          { c0 = p + 1;  c1 = 2*p + 2;   slot = 1; }
    } else {      tile = 15 - p;
      if (half == 0){ c0 = 16 - p; c1 = 32 - 2*p;  slot = 1; }
      else          { c0 = 0;      c1 = 16 - p;    slot = 0; }
    }
    const int qb0 = 2*tile, qb1 = 2*tile + 1;   // diag chunks of the strips
    const int qr0 = tile*128 + w*16 + l16;      // strip 0 query row
    const int qr1 = qr0 + 64;                   // strip 1 query row
    const int nc  = c1 - c0;

    if (ph == 1) __syncthreads();               // prev phase's LDS reads done
    stage(c0, 0);

    bf16x8 qf[2][2];
    qf[0][0] = *(const bf16x8*)(Qh + (size_t)qr0*64 + quad*8);
    qf[0][1] = *(const bf16x8*)(Qh + (size_t)qr0*64 + 32 + quad*8);
    qf[1][0] = *(const bf16x8*)(Qh + (size_t)qr1*64 + quad*8);
    qf[1][1] = *(const bf16x8*)(Qh + (size_t)qr1*64 + 32 + quad*8);

    f32x4 o[2][4];
    #pragma unroll
    for (int s = 0; s < 2; s++)
      for (int dt = 0; dt < 4; dt++) o[s][dt] = (f32x4){0.f, 0.f, 0.f, 0.f};
    float lrow[2] = {0.f, 0.f};

    for (int i = 0; i < nc; i++){
      const int c = c0 + i;
      const int buf = i & 1;
      __syncthreads();                          // DMA(c) arrived; prev reads done
      if (i + 1 < nc) stage(c + 1, buf^1);

      const bool act0  = (c <= qb0);
      const bool diag0 = (c == qb0);
      const bool diag1 = (c == qb1);
      const u16* Kb = &Ks[buf][0];
      const u16* Vb = &Vs[buf][0];

      bf16x4 pk[2][4];
      #pragma unroll
      for (int t = 0; t < 4; t++){
        const bool n0 = act0 && !(diag0 && t > w);
        const bool n1 = !(diag1 && t > w);
        if (!n0 && !n1) continue;
        const int rowb = (t*16 + l16)*64;
        bf16x8 ka0 = *(const bf16x8*)&Kb[rowb + koff0];
        bf16x8 ka1 = *(const bf16x8*)&Kb[rowb + koff1];
        #pragma unroll
        for (int s = 0; s < 2; s++){
          if (s == 0 ? !n0 : !n1) continue;
          f32x4 z = (f32x4){0.f, 0.f, 0.f, 0.f};
          z = __builtin_amdgcn_mfma_f32_16x16x32_bf16(ka0, qf[s][0], z, 0, 0, 0);
          z = __builtin_amdgcn_mfma_f32_16x16x32_bf16(ka1, qf[s][1], z, 0, 0, 0);
          if ((s == 0 ? diag0 : diag1) && t == w){
            #pragma unroll
            for (int r = 0; r < 4; r++)
              if (quad*4 + r > l16) z[r] = -1e30f;  // key > query on the diag
          }
          float p0 = __builtin_amdgcn_exp2f(z[0]);
          float p1 = __builtin_amdgcn_exp2f(z[1]);
          float p2 = __builtin_amdgcn_exp2f(z[2]);
          float p3 = __builtin_amdgcn_exp2f(z[3]);
          lrow[s] += (p0 + p1) + (p2 + p3);
          pk[s][t] = pack4(p0, p1, p2, p3);
        }
      }

      #pragma unroll
      for (int dt = 0; dt < 4; dt++){
        const int rowb = (dt*16 + l16)*64;
        #pragma unroll
        for (int t = 0; t < 4; t++){
          const bool n0 = act0 && !(diag0 && t > w);
          const bool n1 = !(diag1 && t > w);
          if (!n0 && !n1) continue;
          bf16x4 va = *(const bf16x4*)&Vb[rowb + voff[t]];
          if (n0) o[0][dt] = mfma16(va, pk[0][t], o[0][dt]);
          if (n1) o[1][dt] = mfma16(va, pk[1][t], o[1][dt]);
        }
      }
    }

    // phase epilogue: store UNNORMALIZED partial O (bf16) + partial l (fp32)
    u16*   Pd = slot ? P2 : P1;
    float* ld = slot ? l2 : l1;
    #pragma unroll
    for (int s = 0; s < 2; s++){
      float lsum = lrow[s];
      lsum += __shfl_xor(lsum, 16, 64);
      lsum += __shfl_xor(lsum, 32, 64);
      const int qrow = s ? qr1 : qr0;
      if (quad == 0) ld[(size_t)(b*S_ + qrow)*NQ_ + h] = lsum;
      u16* orow = Pd + (size_t)(b*S_ + qrow) * D_ + h*64;
      #pragma unroll
      for (int dt = 0; dt < 4; dt++){
        uint2 pkd;
        u16 e0 = f2b(o[s][dt][0]), e1 = f2b(o[s][dt][1]);
        u16 e2 = f2b(o[s][dt][2]), e3 = f2b(o[s][dt][3]);
        pkd.x = (unsigned)e0 | ((unsigned)e1 << 16);
        pkd.y = (unsigned)e2 | ((unsigned)e3 << 16);
        *(uint2*)(orow + dt*16 + quad*4) = pkd;
      }
    }
  }
}

// ---------------- combine: out = (P1+P2)/(l1+l2), bf16 ----------------
__global__ void k_combine(const u16* __restrict__ P1, const u16* __restrict__ P2,
                          const float* __restrict__ l1, const float* __restrict__ l2,
                          u16* __restrict__ out){
  int i = blockIdx.x * blockDim.x + threadIdx.x;   // < 2,097,152
  int e = i << 2;                                  // element index (4 per thread)
  int li = (e >> 11)*NQ_ + ((e >> 6) & 31);
  float inv = 1.0f / (l1[li] + l2[li]);
  uint2 a = *(const uint2*)(P1 + e);
  uint2 bq = *(const uint2*)(P2 + e);
  float o0 = (b2f(a.x & 0xffff)  + b2f(bq.x & 0xffff))  * inv;
  float o1 = (b2f(a.x >> 16)     + b2f(bq.x >> 16))     * inv;
  float o2 = (b2f(a.y & 0xffff)  + b2f(bq.y & 0xffff))  * inv;
  float o3 = (b2f(a.y >> 16)     + b2f(bq.y >> 16))     * inv;
  uint2 pk;
  pk.x = (unsigned)f2b(o0) | ((unsigned)f2b(o1) << 16);
  pk.y = (unsigned)f2b(o2) | ((unsigned)f2b(o3) << 16);
  *(uint2*)(out + e) = pk;
}

// ---------------- launcher ----------------
extern "C" void kernel_launch(void* const* d_in, const int* in_sizes, int n_in,
                              void* d_out, int out_size, void* d_ws, size_t ws_size,
                              hipStream_t stream){
  const float* x  = (const float*)d_in[0];
  // d_in[1] = attention_mask (all ones; reference never applies it) -> ignored
  const float* Wq = (const float*)d_in[2];
  const float* Wk = (const float*)d_in[3];
  const float* Wv = (const float*)d_in[4];
  const float* Wo = (const float*)d_in[5];

  char* ws = (char*)d_ws;
  u16*   xb    = (u16*)(ws);               // [0,16M)  x bf16 (dead after gemm_qkv)
  u16*   wqkvb = (u16*)(ws + 16777216);    // [16,28M) QKV weights bf16
  u16*   wob   = (u16*)(ws + 29360128);    // [28,36M) Wo bf16 (live till gemm_bt)
  u16*   qTp   = (u16*)(ws + 37748736);    // [36,52M) q RoPE'd (dead after attn)
  u16*   kTp   = (u16*)(ws + 54525952);    // [52,56M) k RoPE'd
  u16*   vTp   = (u16*)(ws + 58720256);    // [56,60M) v transposed
  u16*   P1    = xb;                       // [0,16M)  partial O half0 (over dead xb)
  u16*   P2    = (u16*)(ws + 62914560);    // [60,76M) partial O half1
  float* l1    = (float*)(ws + 79691776);  // 512KB
  float* l2    = (float*)(ws + 80216064);  // 512KB   (high water ~80.7MB < 88 proven)
  u16*   attnOut = qTp;                    // combine writes over dead qTp

  // all fp32 -> bf16 converts in one launch
  k_f2b_all<<<dim3(18432), 256, 0, stream>>>(x, Wq, Wk, Wv, Wo, xb, wqkvb, wob);

  // fused QKV projection + RoPE + V-transpose scatter
  k_gemm_qkv<<<dim3(24, 32), 256, 0, stream>>>(xb, wqkvb, qTp, kTp, vTp);

  // balanced split-K flash attention (uniform 17 chunks/block)
  k_attn<<<dim3(1024), 256, 0, stream>>>(qTp, kTp, vTp, P1, P2, l1, l2);

  // combine partials + normalize
  k_combine<<<dim3(8192), 256, 0, stream>>>(P1, P2, l1, l2, attnOut);

  // output projection: (4096 x 2048) * (2048 x 2048)^T -> fp32 d_out
  k_gemm_bt<<<dim3(16, 32), 256, 0, stream>>>(attnOut, wob, (float*)d_out, 2048);
}

// Round 11
// 295.465 us; speedup vs baseline: 1.0481x; 1.0481x over previous
//
#include <hip/hip_runtime.h>

// Problem constants
#define B_   2
#define S_   2048
#define D_   2048
#define NQ_  32
#define NKV_ 8
#define HD_  64
// g = NQ/NKV = 4

typedef unsigned short u16;
typedef __bf16 bf16x8 __attribute__((ext_vector_type(8)));
typedef short  s16x4  __attribute__((ext_vector_type(4)));
typedef float  f32x4  __attribute__((ext_vector_type(4)));

#define GLB __attribute__((address_space(1)))
#define LDS __attribute__((address_space(3)))

__device__ inline u16 f2b(float f){
  union { float f; unsigned u; } v; v.f = f;
  unsigned r = (v.u + 0x7fffu + ((v.u >> 16) & 1u)) >> 16;
  return (u16)r;
}

// 16x16x16 bf16 MFMA (v_mfma_f32_16x16x16_bf16 on gfx950), raw s16x4 operands
// (no bf16 vector types / union bitcasts in the hot loop).
__device__ inline f32x4 mfma16(s16x4 a, s16x4 b, f32x4 c){
  return __builtin_amdgcn_mfma_f32_16x16x16bf16_1k(a, b, c, 0, 0, 0);
}

// truncation-pack 4 fp32 -> s16x4 bf16 bits (softmax normalization cancels the
// common-mode 2^-9 truncation bias)
__device__ inline s16x4 pack4(float p0, float p1, float p2, float p3){
  union { float f; unsigned u; } a, b, c, d;
  a.f = p0; b.f = p1; c.f = p2; d.f = p3;
  union { uint2 u; s16x4 v; } r;
  r.u.x = (a.u >> 16) | (b.u & 0xffff0000u);
  r.u.y = (c.u >> 16) | (d.u & 0xffff0000u);
  return r.v;
}

// ---------------- fp32 -> bf16 convert, all 5 regions in one launch ---------
__global__ void k_f2b_all(const float* __restrict__ x,  const float* __restrict__ wq,
                          const float* __restrict__ wk, const float* __restrict__ wv,
                          const float* __restrict__ wo,
                          u16* __restrict__ xb, u16* __restrict__ wqkvb, u16* __restrict__ wob){
  int i = blockIdx.x * blockDim.x + threadIdx.x;   // < 4718592
  const float* src; u16* dst; int off;
  if (i < 2097152)      { src = x;  dst = xb;                  off = i; }
  else if (i < 3145728) { src = wq; dst = wqkvb;               off = i - 2097152; }
  else if (i < 3407872) { src = wk; dst = wqkvb + 2048*2048;   off = i - 3145728; }
  else if (i < 3670016) { src = wv; dst = wqkvb + 2560*2048;   off = i - 3407872; }
  else                  { src = wo; dst = wob;                 off = i - 3670016; }
  float4 f = ((const float4*)src)[off];
  uint2 pk;
  pk.x = (unsigned)f2b(f.x) | ((unsigned)f2b(f.y) << 16);
  pk.y = (unsigned)f2b(f.z) | ((unsigned)f2b(f.w) << 16);
  ((uint2*)dst)[off] = pk;
}

// ======================= shared GEMM core (BK=64, swizzled) =================
// LDS: chunk s of row r holds GLOBAL chunk s^(r&7); DMA permutes the global
// column per lane (LDS side stays the required contiguous lane*16B pattern).
#define GEMM_CORE(K)                                                           \
  __shared__ __align__(16) u16 As[128*64];                                     \
  __shared__ __align__(16) u16 Bs[128*64];                                     \
  const int tid  = threadIdx.x;                                               \
  const int lane = tid & 63;                                                  \
  const int wave = tid >> 6;                                                  \
  const int wm = wave >> 1, wn = wave & 1;                                    \
  const int quad = lane >> 4, l16 = lane & 15;                                \
  const u16* Ab = A  + (size_t)blockIdx.y * 128 * (K);                        \
  const u16* Bb = Bm + (size_t)blockIdx.x * 128 * (K);                        \
  f32x4 acc[4][4];                                                            \
  for (int i = 0; i < 4; i++)                                                 \
    for (int j = 0; j < 4; j++) acc[i][j] = (f32x4){0.f, 0.f, 0.f, 0.f};      \
  const int R0 = wave * 32;                                                   \
  const int lr = lane >> 3;                                                   \
  const int gc = ((lane & 7) ^ lr) * 8;                                       \
  const int sk = l16 & 7;                                                     \
  for (int k0 = 0; k0 < (K); k0 += 64){                                       \
    __syncthreads();                                                          \
    _Pragma("unroll")                                                         \
    for (int m = 0; m < 4; m++){                                              \
      const u16* ga = Ab + (size_t)(R0 + m*8 + lr) * (K) + k0 + gc;           \
      const u16* gb = Bb + (size_t)(R0 + m*8 + lr) * (K) + k0 + gc;           \
      __builtin_amdgcn_global_load_lds((const GLB void*)ga, (LDS void*)&As[(R0 + m*8)*64], 16, 0, 0); \
      __builtin_amdgcn_global_load_lds((const GLB void*)gb, (LDS void*)&Bs[(R0 + m*8)*64], 16, 0, 0); \
    }                                                                          \
    __syncthreads();                                                          \
    bf16x8 af[4][2], bfr[4][2];                                               \
    _Pragma("unroll")                                                         \
    for (int i = 0; i < 4; i++)                                               \
      _Pragma("unroll")                                                       \
      for (int h = 0; h < 2; h++)                                             \
        af[i][h]  = *(const bf16x8*)&As[(wm*64 + i*16 + l16)*64 + (((h*4 + quad) ^ sk)*8)]; \
    _Pragma("unroll")                                                         \
    for (int j = 0; j < 4; j++)                                               \
      _Pragma("unroll")                                                       \
      for (int h = 0; h < 2; h++)                                             \
        bfr[j][h] = *(const bf16x8*)&Bs[(wn*64 + j*16 + l16)*64 + (((h*4 + quad) ^ sk)*8)]; \
    _Pragma("unroll")                                                         \
    for (int i = 0; i < 4; i++)                                               \
      _Pragma("unroll")                                                       \
      for (int j = 0; j < 4; j++){                                            \
        acc[i][j] = __builtin_amdgcn_mfma_f32_16x16x32_bf16(af[i][0], bfr[j][0], acc[i][j], 0, 0, 0); \
        acc[i][j] = __builtin_amdgcn_mfma_f32_16x16x32_bf16(af[i][1], bfr[j][1], acc[i][j], 0, 0, 0); \
      }                                                                        \
  }

// ---------------- fused QKV GEMM + RoPE + scatter ----------------
#define QSCALE 0.18033688011112042f
__global__ __launch_bounds__(256, 3) void k_gemm_qkv(const u16* __restrict__ A,
                                                     const u16* __restrict__ Bm,
                                                     u16* __restrict__ qT,
                                                     u16* __restrict__ kT,
                                                     u16* __restrict__ vT){
  GEMM_CORE(2048)

  // ---- fused epilogue ----
  const int cb = blockIdx.x*128 + wn*64;   // wave's 64-col span = one head

  if (cb < 2560){
    const bool isq = (cb < 2048);
    const int hh   = (isq ? cb : (cb - 2048)) >> 6;
    const int NH   = isq ? NQ_ : NKV_;
    u16* base      = isq ? qT : kT;
    const float sc = isq ? QSCALE : 1.0f;
    #pragma unroll
    for (int j = 0; j < 2; j++){
      const int d2 = j*16 + l16;
      const float invf = __expf(-(float)d2 * (9.210340371976184f / 32.0f));
      #pragma unroll
      for (int i = 0; i < 4; i++){
        const int row0 = blockIdx.y*128 + wm*64 + i*16 + quad*4;
        #pragma unroll
        for (int r = 0; r < 4; r++){
          const int row = row0 + r;
          const int s = row & (S_ - 1), b = row >> 11;
          float ang = (float)s * invf;
          float sn = __sinf(ang), cs = __cosf(ang);   // hw v_sin/v_cos
          const float x1 = acc[i][j][r] * sc, x2 = acc[i][j+2][r] * sc;
          u16* drow = base + ((size_t)(b*NH + hh) * S_ + s) * 64;
          drow[d2]      = f2b(x1*cs - x2*sn);
          drow[d2 + 32] = f2b(x2*cs + x1*sn);
        }
      }
    }
  } else {
    const int fbase = cb - 2560;
    #pragma unroll
    for (int j = 0; j < 4; j++){
      const int f = fbase + j*16 + l16;
      const int kvh = f >> 6, d = f & 63;
      #pragma unroll
      for (int i = 0; i < 4; i++){
        const int row0 = blockIdx.y*128 + wm*64 + i*16 + quad*4;
        const int s0 = row0 & (S_ - 1), b = row0 >> 11;
        uint2 pk;
        pk.x = (unsigned)f2b(acc[i][j][0]) | ((unsigned)f2b(acc[i][j][1]) << 16);
        pk.y = (unsigned)f2b(acc[i][j][2]) | ((unsigned)f2b(acc[i][j][3]) << 16);
        *(uint2*)(vT + ((size_t)(b*NKV_ + kvh) * 64 + d) * S_ + s0) = pk;
      }
    }
  }
}

// ---------------- out-proj GEMM: fp32 epilogue ----------------
__global__ __launch_bounds__(256, 3) void k_gemm_bt(const u16* __restrict__ A,
                                                    const u16* __restrict__ Bm,
                                                    float* __restrict__ C,
                                                    int N){
  GEMM_CORE(2048)
  for (int i = 0; i < 4; i++){
    int row0 = blockIdx.y*128 + wm*64 + i*16 + quad*4;
    for (int j = 0; j < 4; j++){
      int col = blockIdx.x*128 + wn*64 + j*16 + l16;
      for (int r = 0; r < 4; r++)
        C[(size_t)(row0 + r) * N + col] = acc[i][j][r];
    }
  }
}

// ---------------- flash attention (causal, GQA), 128q single-tile blocks ----
// Round-9 structure (best measured: 93us). Grid: 1024 blocks = 16 tiles x 64
// (b,h) -> 4 blocks/CU. T = 15-(bid>>6): longest tiles dispatch first (LPT
// backfill). kvh = bid&7 -> KV-head XCD locality (FETCH 38->12MB measured).
// Each wave owns TWO 16-query strips (tile offset 0/64); K/V LDS reads shared
// across strips. Fixed-max softmax (Q pre-scaled by log2e/8 -> exp2 direct).
__global__ __launch_bounds__(256) void k_attn(const u16* __restrict__ qT,
                                              const u16* __restrict__ kT,
                                              const u16* __restrict__ vT,
                                              u16* __restrict__ aout){
  __shared__ __align__(16) u16 Ks[2][64*64];
  __shared__ __align__(16) u16 Vs[2][64*64];

  const int bid = blockIdx.x;
  const int kvh = bid & 7;
  const int b   = (bid >> 3) & 1;
  const int hq  = (bid >> 4) & 3;
  const int T   = 15 - (bid >> 6);
  const int h   = kvh*4 + hq;
  const int lane = threadIdx.x & 63, w = threadIdx.x >> 6;
  const int quad = lane >> 4, l16 = lane & 15;

  const u16* Qh = qT + (size_t)(b*NQ_ + h)    * S_ * 64;
  const u16* Kh = kT + (size_t)(b*NKV_ + kvh) * S_ * 64;
  const u16* Vh = vT + (size_t)(b*NKV_ + kvh) * 64 * S_;

  const int rr = lane >> 3;
  const int gg = (lane & 7) ^ rr;
  const int R  = w * 16;

  auto stage = [&](int c, int buf){
    const int kb = c * 64;
    const u16* gk0 = Kh + (size_t)(kb + R + rr)     * 64 + gg*8;
    const u16* gk1 = Kh + (size_t)(kb + R + 8 + rr) * 64 + gg*8;
    const u16* gv0 = Vh + (size_t)(R + rr)     * S_ + kb + gg*8;
    const u16* gv1 = Vh + (size_t)(R + 8 + rr) * S_ + kb + gg*8;
    __builtin_amdgcn_global_load_lds((const GLB void*)gk0, (LDS void*)&Ks[buf][R*64],     16, 0, 0);
    __builtin_amdgcn_global_load_lds((const GLB void*)gk1, (LDS void*)&Ks[buf][(R+8)*64], 16, 0, 0);
    __builtin_amdgcn_global_load_lds((const GLB void*)gv0, (LDS void*)&Vs[buf][R*64],     16, 0, 0);
    __builtin_amdgcn_global_load_lds((const GLB void*)gv1, (LDS void*)&Vs[buf][(R+8)*64], 16, 0, 0);
  };

  // hoisted chunk-invariant swizzled offsets (u16 units)
  const int sw    = l16 & 7;
  const int koff0 = ((quad    ) ^ sw) * 8;
  const int koff1 = ((quad + 4) ^ sw) * 8;

  const int qb0 = 2*T, qb1 = 2*T + 1;       // diag chunk of strip 0 / strip 1
  const int qr0 = T*128 + w*16 + l16;       // strip 0 query row
  const int qr1 = qr0 + 64;                 // strip 1 query row

  stage(0, 0);

  bf16x8 qf[2][2];
  qf[0][0] = *(const bf16x8*)(Qh + (size_t)qr0*64 + quad*8);
  qf[0][1] = *(const bf16x8*)(Qh + (size_t)qr0*64 + 32 + quad*8);
  qf[1][0] = *(const bf16x8*)(Qh + (size_t)qr1*64 + quad*8);
  qf[1][1] = *(const bf16x8*)(Qh + (size_t)qr1*64 + 32 + quad*8);

  f32x4 o[2][4];
  #pragma unroll
  for (int s = 0; s < 2; s++)
    for (int dt = 0; dt < 4; dt++) o[s][dt] = (f32x4){0.f, 0.f, 0.f, 0.f};
  float lrow[2] = {0.f, 0.f};

  for (int c = 0; c <= qb1; c++){
    const int buf = c & 1;
    __syncthreads();                        // DMA(c) arrived; prev reads done
    if (c < qb1) stage(c+1, buf^1);

    const bool act0  = (c <= qb0);
    const bool diag0 = (c == qb0);
    const bool diag1 = (c == qb1);
    const u16* Kb = &Ks[buf][0];
    const u16* Vb = &Vs[buf][0];

    s16x4 pk[2][4];
    #pragma unroll
    for (int t = 0; t < 4; t++){
      const bool n0 = act0 && !(diag0 && t > w);
      const bool n1 = !(diag1 && t > w);
      if (!n0 && !n1) continue;
      const int rowb = (t*16 + l16)*64;
      bf16x8 ka0 = *(const bf16x8*)&Kb[rowb + koff0];
      bf16x8 ka1 = *(const bf16x8*)&Kb[rowb + koff1];
      #pragma unroll
      for (int s = 0; s < 2; s++){
        if (s == 0 ? !n0 : !n1) continue;
        f32x4 z = (f32x4){0.f, 0.f, 0.f, 0.f};
        z = __builtin_amdgcn_mfma_f32_16x16x32_bf16(ka0, qf[s][0], z, 0, 0, 0);
        z = __builtin_amdgcn_mfma_f32_16x16x32_bf16(ka1, qf[s][1], z, 0, 0, 0);
        if ((s == 0 ? diag0 : diag1) && t == w){
          #pragma unroll
          for (int r = 0; r < 4; r++)
            if (quad*4 + r > l16) z[r] = -1e30f;   // key > query on the diag
        }
        float p0 = __builtin_amdgcn_exp2f(z[0]);
        float p1 = __builtin_amdgcn_exp2f(z[1]);
        float p2 = __builtin_amdgcn_exp2f(z[2]);
        float p3 = __builtin_amdgcn_exp2f(z[3]);
        lrow[s] += (p0 + p1) + (p2 + p3);
        pk[s][t] = pack4(p0, p1, p2, p3);
      }
    }

    #pragma unroll
    for (int dt = 0; dt < 4; dt++){
      const int rowb = (dt*16 + l16)*64;
      #pragma unroll
      for (int t = 0; t < 4; t++){
        const bool n0 = act0 && !(diag0 && t > w);
        const bool n1 = !(diag1 && t > w);
        if (!n0 && !n1) continue;
        const int vo = (((2*t + (quad >> 1)) ^ sw) * 8) + (quad & 1)*4;
        s16x4 va = *(const s16x4*)&Vb[rowb + vo];
        if (n0) o[0][dt] = mfma16(va, pk[0][t], o[0][dt]);
        if (n1) o[1][dt] = mfma16(va, pk[1][t], o[1][dt]);
      }
    }
  }

  #pragma unroll
  for (int s = 0; s < 2; s++){
    float lsum = lrow[s];
    lsum += __shfl_xor(lsum, 16, 64);
    lsum += __shfl_xor(lsum, 32, 64);
    float inv = 1.0f / lsum;
    const int qrow = s ? qr1 : qr0;
    u16* orow = aout + (size_t)(b*S_ + qrow) * D_ + h*64;
    #pragma unroll
    for (int dt = 0; dt < 4; dt++){
      uint2 pkd;
      u16 e0 = f2b(o[s][dt][0] * inv), e1 = f2b(o[s][dt][1] * inv);
      u16 e2 = f2b(o[s][dt][2] * inv), e3 = f2b(o[s][dt][3] * inv);
      pkd.x = (unsigned)e0 | ((unsigned)e1 << 16);
      pkd.y = (unsigned)e2 | ((unsigned)e3 << 16);
      *(uint2*)(orow + dt*16 + quad*4) = pkd;
    }
  }
}

// ---------------- launcher ----------------
extern "C" void kernel_launch(void* const* d_in, const int* in_sizes, int n_in,
                              void* d_out, int out_size, void* d_ws, size_t ws_size,
                              hipStream_t stream){
  const float* x  = (const float*)d_in[0];
  // d_in[1] = attention_mask (all ones; reference never applies it) -> ignored
  const float* Wq = (const float*)d_in[2];
  const float* Wk = (const float*)d_in[3];
  const float* Wv = (const float*)d_in[4];
  const float* Wo = (const float*)d_in[5];

  char* ws = (char*)d_ws;
  u16* xb    = (u16*)(ws);               // 16 MB, x bf16; reused as attnOut after GEMM1
  u16* wqkvb = (u16*)(ws + 16777216);    // 12 MB, [Wq;Wk;Wv] bf16 (3072 x 2048)
  u16* wob   = (u16*)(ws + 29360128);    // 8 MB, Wo bf16
  u16* qTp   = (u16*)(ws + 37748736);    // 16 MB, q (b,h,s,64) RoPE'd + pre-scaled
  u16* kTp   = (u16*)(ws + 54525952);    // 4 MB,  k (b,kvh,s,64) RoPE'd
  u16* vTp   = (u16*)(ws + 58720256);    // 4 MB,  v (b,kvh,64,s)
  u16* attnOut = xb;                     // alias: xb dead after GEMM1

  // all fp32 -> bf16 converts in one launch
  k_f2b_all<<<dim3(18432), 256, 0, stream>>>(x, Wq, Wk, Wv, Wo, xb, wqkvb, wob);

  // fused QKV projection + RoPE + V-transpose scatter
  k_gemm_qkv<<<dim3(24, 32), 256, 0, stream>>>(xb, wqkvb, qTp, kTp, vTp);

  // causal GQA flash attention: 128q tiles, longest-first, XCD-local KV
  k_attn<<<dim3(1024), 256, 0, stream>>>(qTp, kTp, vTp, attnOut);

  // output projection: (4096 x 2048) * (2048 x 2048)^T -> fp32 d_out
  k_gemm_bt<<<dim3(16, 32), 256, 0, stream>>>(attnOut, wob, (float*)d_out, 2048);
}

// Round 12
// 288.400 us; speedup vs baseline: 1.0738x; 1.0245x over previous
//
#include <hip/hip_runtime.h>

// Problem constants
#define B_   2
#define S_   2048
#define D_   2048
#define NQ_  32
#define NKV_ 8
#define HD_  64
// g = NQ/NKV = 4

typedef unsigned short u16;
typedef __bf16 bf16x8 __attribute__((ext_vector_type(8)));
typedef short  s16x4  __attribute__((ext_vector_type(4)));
typedef float  f32x4  __attribute__((ext_vector_type(4)));

#define GLB __attribute__((address_space(1)))
#define LDS __attribute__((address_space(3)))

__device__ inline u16 f2b(float f){
  union { float f; unsigned u; } v; v.f = f;
  unsigned r = (v.u + 0x7fffu + ((v.u >> 16) & 1u)) >> 16;
  return (u16)r;
}
__device__ inline float b2f(u16 b){
  union { unsigned u; float f; } v; v.u = ((unsigned)b) << 16;
  return v.f;
}

// 16x16x16 bf16 MFMA (v_mfma_f32_16x16x16_bf16 on gfx950), raw s16x4 operands.
// NOTE: no __has_builtin guard — it checks the HOST target in HIP and lies.
__device__ inline f32x4 mfma16(s16x4 a, s16x4 b, f32x4 c){
  return __builtin_amdgcn_mfma_f32_16x16x16bf16_1k(a, b, c, 0, 0, 0);
}

// truncation-pack 4 fp32 -> s16x4 bf16 bits (softmax normalization cancels the
// common-mode 2^-9 truncation bias)
__device__ inline s16x4 pack4(float p0, float p1, float p2, float p3){
  union { float f; unsigned u; } a, b, c, d;
  a.f = p0; b.f = p1; c.f = p2; d.f = p3;
  union { uint2 u; s16x4 v; } r;
  r.u.x = (a.u >> 16) | (b.u & 0xffff0000u);
  r.u.y = (c.u >> 16) | (d.u & 0xffff0000u);
  return r.v;
}

// ---------------- fp32 -> bf16 convert, all 5 regions in one launch ---------
__global__ void k_f2b_all(const float* __restrict__ x,  const float* __restrict__ wq,
                          const float* __restrict__ wk, const float* __restrict__ wv,
                          const float* __restrict__ wo,
                          u16* __restrict__ xb, u16* __restrict__ wqkvb, u16* __restrict__ wob){
  int i = blockIdx.x * blockDim.x + threadIdx.x;   // < 4718592
  const float* src; u16* dst; int off;
  if (i < 2097152)      { src = x;  dst = xb;                  off = i; }
  else if (i < 3145728) { src = wq; dst = wqkvb;               off = i - 2097152; }
  else if (i < 3407872) { src = wk; dst = wqkvb + 2048*2048;   off = i - 3145728; }
  else if (i < 3670016) { src = wv; dst = wqkvb + 2560*2048;   off = i - 3407872; }
  else                  { src = wo; dst = wob;                 off = i - 3670016; }
  float4 f = ((const float4*)src)[off];
  uint2 pk;
  pk.x = (unsigned)f2b(f.x) | ((unsigned)f2b(f.y) << 16);
  pk.y = (unsigned)f2b(f.z) | ((unsigned)f2b(f.w) << 16);
  ((uint2*)dst)[off] = pk;
}

// ======================= shared GEMM core (BK=64, swizzled) =================
// LDS: chunk s of row r holds GLOBAL chunk s^(r&7); DMA permutes the global
// column per lane (LDS side stays the required contiguous lane*16B pattern).
#define GEMM_CORE(K)                                                           \
  __shared__ __align__(16) u16 As[128*64];                                     \
  __shared__ __align__(16) u16 Bs[128*64];                                     \
  const int tid  = threadIdx.x;                                               \
  const int lane = tid & 63;                                                  \
  const int wave = tid >> 6;                                                  \
  const int wm = wave >> 1, wn = wave & 1;                                    \
  const int quad = lane >> 4, l16 = lane & 15;                                \
  const u16* Ab = A  + (size_t)blockIdx.y * 128 * (K);                        \
  const u16* Bb = Bm + (size_t)blockIdx.x * 128 * (K);                        \
  f32x4 acc[4][4];                                                            \
  for (int i = 0; i < 4; i++)                                                 \
    for (int j = 0; j < 4; j++) acc[i][j] = (f32x4){0.f, 0.f, 0.f, 0.f};      \
  const int R0 = wave * 32;                                                   \
  const int lr = lane >> 3;                                                   \
  const int gc = ((lane & 7) ^ lr) * 8;                                       \
  const int sk = l16 & 7;                                                     \
  for (int k0 = 0; k0 < (K); k0 += 64){                                       \
    __syncthreads();                                                          \
    _Pragma("unroll")                                                         \
    for (int m = 0; m < 4; m++){                                              \
      const u16* ga = Ab + (size_t)(R0 + m*8 + lr) * (K) + k0 + gc;           \
      const u16* gb = Bb + (size_t)(R0 + m*8 + lr) * (K) + k0 + gc;           \
      __builtin_amdgcn_global_load_lds((const GLB void*)ga, (LDS void*)&As[(R0 + m*8)*64], 16, 0, 0); \
      __builtin_amdgcn_global_load_lds((const GLB void*)gb, (LDS void*)&Bs[(R0 + m*8)*64], 16, 0, 0); \
    }                                                                          \
    __syncthreads();                                                          \
    bf16x8 af[4][2], bfr[4][2];                                               \
    _Pragma("unroll")                                                         \
    for (int i = 0; i < 4; i++)                                               \
      _Pragma("unroll")                                                       \
      for (int h = 0; h < 2; h++)                                             \
        af[i][h]  = *(const bf16x8*)&As[(wm*64 + i*16 + l16)*64 + (((h*4 + quad) ^ sk)*8)]; \
    _Pragma("unroll")                                                         \
    for (int j = 0; j < 4; j++)                                               \
      _Pragma("unroll")                                                       \
      for (int h = 0; h < 2; h++)                                             \
        bfr[j][h] = *(const bf16x8*)&Bs[(wn*64 + j*16 + l16)*64 + (((h*4 + quad) ^ sk)*8)]; \
    _Pragma("unroll")                                                         \
    for (int i = 0; i < 4; i++)                                               \
      _Pragma("unroll")                                                       \
      for (int j = 0; j < 4; j++){                                            \
        acc[i][j] = __builtin_amdgcn_mfma_f32_16x16x32_bf16(af[i][0], bfr[j][0], acc[i][j], 0, 0, 0); \
        acc[i][j] = __builtin_amdgcn_mfma_f32_16x16x32_bf16(af[i][1], bfr[j][1], acc[i][j], 0, 0, 0); \
      }                                                                        \
  }

// ---------------- fused QKV GEMM + RoPE + scatter ----------------
#define QSCALE 0.18033688011112042f
__global__ __launch_bounds__(256, 3) void k_gemm_qkv(const u16* __restrict__ A,
                                                     const u16* __restrict__ Bm,
                                                     u16* __restrict__ qT,
                                                     u16* __restrict__ kT,
                                                     u16* __restrict__ vT){
  GEMM_CORE(2048)

  // ---- fused epilogue ----
  const int cb = blockIdx.x*128 + wn*64;   // wave's 64-col span = one head

  if (cb < 2560){
    const bool isq = (cb < 2048);
    const int hh   = (isq ? cb : (cb - 2048)) >> 6;
    const int NH   = isq ? NQ_ : NKV_;
    u16* base      = isq ? qT : kT;
    const float sc = isq ? QSCALE : 1.0f;
    #pragma unroll
    for (int j = 0; j < 2; j++){
      const int d2 = j*16 + l16;
      const float invf = __expf(-(float)d2 * (9.210340371976184f / 32.0f));
      #pragma unroll
      for (int i = 0; i < 4; i++){
        const int row0 = blockIdx.y*128 + wm*64 + i*16 + quad*4;
        #pragma unroll
        for (int r = 0; r < 4; r++){
          const int row = row0 + r;
          const int s = row & (S_ - 1), b = row >> 11;
          float ang = (float)s * invf;
          float sn = __sinf(ang), cs = __cosf(ang);   // hw v_sin/v_cos
          const float x1 = acc[i][j][r] * sc, x2 = acc[i][j+2][r] * sc;
          u16* drow = base + ((size_t)(b*NH + hh) * S_ + s) * 64;
          drow[d2]      = f2b(x1*cs - x2*sn);
          drow[d2 + 32] = f2b(x2*cs + x1*sn);
        }
      }
    }
  } else {
    const int fbase = cb - 2560;
    #pragma unroll
    for (int j = 0; j < 4; j++){
      const int f = fbase + j*16 + l16;
      const int kvh = f >> 6, d = f & 63;
      #pragma unroll
      for (int i = 0; i < 4; i++){
        const int row0 = blockIdx.y*128 + wm*64 + i*16 + quad*4;
        const int s0 = row0 & (S_ - 1), b = row0 >> 11;
        uint2 pk;
        pk.x = (unsigned)f2b(acc[i][j][0]) | ((unsigned)f2b(acc[i][j][1]) << 16);
        pk.y = (unsigned)f2b(acc[i][j][2]) | ((unsigned)f2b(acc[i][j][3]) << 16);
        *(uint2*)(vT + ((size_t)(b*NKV_ + kvh) * 64 + d) * S_ + s0) = pk;
      }
    }
  }
}

// ---------------- out-proj GEMM: fp32 epilogue ----------------
__global__ __launch_bounds__(256, 3) void k_gemm_bt(const u16* __restrict__ A,
                                                    const u16* __restrict__ Bm,
                                                    float* __restrict__ C,
                                                    int N){
  GEMM_CORE(2048)
  for (int i = 0; i < 4; i++){
    int row0 = blockIdx.y*128 + wm*64 + i*16 + quad*4;
    for (int j = 0; j < 4; j++){
      int col = blockIdx.x*128 + wn*64 + j*16 + l16;
      for (int r = 0; r < 4; r++)
        C[(size_t)(row0 + r) * N + col] = acc[i][j][r];
    }
  }
}

// ---------------- flash attention: split-K, 2048 oversubscribed blocks ------
// Fixed-max softmax => partial (O,l) over disjoint key ranges simply ADD.
// Tile T (128 queries) needs chunks [0, 2T+2); half0 = [0,T+1) -> (P1,l1),
// half1 = [T+1,2T+2) -> (P2,l2). One half-job per block: 2048 blocks with
// lengths 1..16 chunks, LONGEST FIRST (j = bid>>6, T = 15-(j>>1)) so the HW
// backfills short jobs behind long ones (grid ~2x residency capacity — fixes
// round-11's 27% occupancy, where grid==capacity made LPT a no-op).
// kvh = bid&7 -> KV-head XCD locality. K/V ranges of the two halves are
// disjoint -> no duplicate K/V fetch. k_combine adds partials + normalizes.
__global__ __launch_bounds__(256) void k_attn(const u16* __restrict__ qT,
                                              const u16* __restrict__ kT,
                                              const u16* __restrict__ vT,
                                              u16* __restrict__ P1,
                                              u16* __restrict__ P2,
                                              float* __restrict__ l1,
                                              float* __restrict__ l2){
  __shared__ __align__(16) u16 Ks[2][64*64];
  __shared__ __align__(16) u16 Vs[2][64*64];

  const int bid  = blockIdx.x;
  const int kvh  = bid & 7;
  const int b    = (bid >> 3) & 1;
  const int hq   = (bid >> 4) & 3;
  const int j    = bid >> 6;            // 0..31, job index
  const int T    = 15 - (j >> 1);       // longest tiles first
  const int half = j & 1;
  const int h    = kvh*4 + hq;
  const int lane = threadIdx.x & 63, w = threadIdx.x >> 6;
  const int quad = lane >> 4, l16 = lane & 15;

  const u16* Qh = qT + (size_t)(b*NQ_ + h)    * S_ * 64;
  const u16* Kh = kT + (size_t)(b*NKV_ + kvh) * S_ * 64;
  const u16* Vh = vT + (size_t)(b*NKV_ + kvh) * 64 * S_;

  const int rr = lane >> 3;
  const int gg = (lane & 7) ^ rr;
  const int R  = w * 16;

  auto stage = [&](int c, int buf){
    const int kb = c * 64;
    const u16* gk0 = Kh + (size_t)(kb + R + rr)     * 64 + gg*8;
    const u16* gk1 = Kh + (size_t)(kb + R + 8 + rr) * 64 + gg*8;
    const u16* gv0 = Vh + (size_t)(R + rr)     * S_ + kb + gg*8;
    const u16* gv1 = Vh + (size_t)(R + 8 + rr) * S_ + kb + gg*8;
    __builtin_amdgcn_global_load_lds((const GLB void*)gk0, (LDS void*)&Ks[buf][R*64],     16, 0, 0);
    __builtin_amdgcn_global_load_lds((const GLB void*)gk1, (LDS void*)&Ks[buf][(R+8)*64], 16, 0, 0);
    __builtin_amdgcn_global_load_lds((const GLB void*)gv0, (LDS void*)&Vs[buf][R*64],     16, 0, 0);
    __builtin_amdgcn_global_load_lds((const GLB void*)gv1, (LDS void*)&Vs[buf][(R+8)*64], 16, 0, 0);
  };

  // hoisted chunk-invariant swizzled offsets (u16 units)
  const int sw    = l16 & 7;
  const int koff0 = ((quad    ) ^ sw) * 8;
  const int koff1 = ((quad + 4) ^ sw) * 8;

  const int qb0 = 2*T, qb1 = 2*T + 1;     // diag chunks of strip 0 / strip 1
  const int qr0 = T*128 + w*16 + l16;     // strip 0 query row
  const int qr1 = qr0 + 64;               // strip 1 query row
  const int c0  = half ? (T + 1) : 0;     // this job's chunk range
  const int nc  = T + 1;

  stage(c0, 0);

  bf16x8 qf[2][2];
  qf[0][0] = *(const bf16x8*)(Qh + (size_t)qr0*64 + quad*8);
  qf[0][1] = *(const bf16x8*)(Qh + (size_t)qr0*64 + 32 + quad*8);
  qf[1][0] = *(const bf16x8*)(Qh + (size_t)qr1*64 + quad*8);
  qf[1][1] = *(const bf16x8*)(Qh + (size_t)qr1*64 + 32 + quad*8);

  f32x4 o[2][4];
  #pragma unroll
  for (int s = 0; s < 2; s++)
    for (int dt = 0; dt < 4; dt++) o[s][dt] = (f32x4){0.f, 0.f, 0.f, 0.f};
  float lrow[2] = {0.f, 0.f};

  for (int i = 0; i < nc; i++){
    const int c = c0 + i;
    const int buf = i & 1;
    __syncthreads();                      // DMA(c) arrived; prev reads done
    if (i + 1 < nc) stage(c + 1, buf^1);

    const bool act0  = (c <= qb0);
    const bool diag0 = (c == qb0);
    const bool diag1 = (c == qb1);
    const u16* Kb = &Ks[buf][0];
    const u16* Vb = &Vs[buf][0];

    s16x4 pk[2][4];
    #pragma unroll
    for (int t = 0; t < 4; t++){
      const bool n0 = act0 && !(diag0 && t > w);
      const bool n1 = !(diag1 && t > w);
      if (!n0 && !n1) continue;
      const int rowb = (t*16 + l16)*64;
      bf16x8 ka0 = *(const bf16x8*)&Kb[rowb + koff0];
      bf16x8 ka1 = *(const bf16x8*)&Kb[rowb + koff1];
      #pragma unroll
      for (int s = 0; s < 2; s++){
        if (s == 0 ? !n0 : !n1) continue;
        f32x4 z = (f32x4){0.f, 0.f, 0.f, 0.f};
        z = __builtin_amdgcn_mfma_f32_16x16x32_bf16(ka0, qf[s][0], z, 0, 0, 0);
        z = __builtin_amdgcn_mfma_f32_16x16x32_bf16(ka1, qf[s][1], z, 0, 0, 0);
        if ((s == 0 ? diag0 : diag1) && t == w){
          #pragma unroll
          for (int r = 0; r < 4; r++)
            if (quad*4 + r > l16) z[r] = -1e30f;   // key > query on the diag
        }
        float p0 = __builtin_amdgcn_exp2f(z[0]);
        float p1 = __builtin_amdgcn_exp2f(z[1]);
        float p2 = __builtin_amdgcn_exp2f(z[2]);
        float p3 = __builtin_amdgcn_exp2f(z[3]);
        lrow[s] += (p0 + p1) + (p2 + p3);
        pk[s][t] = pack4(p0, p1, p2, p3);
      }
    }

    #pragma unroll
    for (int dt = 0; dt < 4; dt++){
      const int rowb = (dt*16 + l16)*64;
      #pragma unroll
      for (int t = 0; t < 4; t++){
        const bool n0 = act0 && !(diag0 && t > w);
        const bool n1 = !(diag1 && t > w);
        if (!n0 && !n1) continue;
        const int vo = (((2*t + (quad >> 1)) ^ sw) * 8) + (quad & 1)*4;
        s16x4 va = *(const s16x4*)&Vb[rowb + vo];
        if (n0) o[0][dt] = mfma16(va, pk[0][t], o[0][dt]);
        if (n1) o[1][dt] = mfma16(va, pk[1][t], o[1][dt]);
      }
    }
  }

  // store UNNORMALIZED partial O (bf16) + partial l (fp32) to this half's slot
  u16*   Pd = half ? P2 : P1;
  float* ld = half ? l2 : l1;
  #pragma unroll
  for (int s = 0; s < 2; s++){
    float lsum = lrow[s];
    lsum += __shfl_xor(lsum, 16, 64);
    lsum += __shfl_xor(lsum, 32, 64);
    const int qrow = s ? qr1 : qr0;
    if (quad == 0) ld[(size_t)(b*S_ + qrow)*NQ_ + h] = lsum;
    u16* orow = Pd + (size_t)(b*S_ + qrow) * D_ + h*64;
    #pragma unroll
    for (int dt = 0; dt < 4; dt++){
      uint2 pkd;
      u16 e0 = f2b(o[s][dt][0]), e1 = f2b(o[s][dt][1]);
      u16 e2 = f2b(o[s][dt][2]), e3 = f2b(o[s][dt][3]);
      pkd.x = (unsigned)e0 | ((unsigned)e1 << 16);
      pkd.y = (unsigned)e2 | ((unsigned)e3 << 16);
      *(uint2*)(orow + dt*16 + quad*4) = pkd;
    }
  }
}

// ---------------- combine: out = (P1+P2)/(l1+l2), bf16 ----------------
__global__ void k_combine(const u16* __restrict__ P1, const u16* __restrict__ P2,
                          const float* __restrict__ l1, const float* __restrict__ l2,
                          u16* __restrict__ out){
  int i = blockIdx.x * blockDim.x + threadIdx.x;   // < 2,097,152
  int e = i << 2;                                  // element index (4 per thread)
  int li = (e >> 11)*NQ_ + ((e >> 6) & 31);
  float inv = 1.0f / (l1[li] + l2[li]);
  uint2 a = *(const uint2*)(P1 + e);
  uint2 bq = *(const uint2*)(P2 + e);
  float o0 = (b2f(a.x & 0xffff)  + b2f(bq.x & 0xffff))  * inv;
  float o1 = (b2f(a.x >> 16)     + b2f(bq.x >> 16))     * inv;
  float o2 = (b2f(a.y & 0xffff)  + b2f(bq.y & 0xffff))  * inv;
  float o3 = (b2f(a.y >> 16)     + b2f(bq.y >> 16))     * inv;
  uint2 pk;
  pk.x = (unsigned)f2b(o0) | ((unsigned)f2b(o1) << 16);
  pk.y = (unsigned)f2b(o2) | ((unsigned)f2b(o3) << 16);
  *(uint2*)(out + e) = pk;
}

// ---------------- launcher ----------------
extern "C" void kernel_launch(void* const* d_in, const int* in_sizes, int n_in,
                              void* d_out, int out_size, void* d_ws, size_t ws_size,
                              hipStream_t stream){
  const float* x  = (const float*)d_in[0];
  // d_in[1] = attention_mask (all ones; reference never applies it) -> ignored
  const float* Wq = (const float*)d_in[2];
  const float* Wk = (const float*)d_in[3];
  const float* Wv = (const float*)d_in[4];
  const float* Wo = (const float*)d_in[5];

  char* ws = (char*)d_ws;
  u16*   xb    = (u16*)(ws);               // [0,16M)  x bf16 (dead after gemm_qkv)
  u16*   wqkvb = (u16*)(ws + 16777216);    // [16,28M) QKV weights bf16
  u16*   wob   = (u16*)(ws + 29360128);    // [28,36M) Wo bf16 (live till gemm_bt)
  u16*   qTp   = (u16*)(ws + 37748736);    // [36,52M) q RoPE'd (dead after attn)
  u16*   kTp   = (u16*)(ws + 54525952);    // [52,56M) k RoPE'd
  u16*   vTp   = (u16*)(ws + 58720256);    // [56,60M) v transposed
  u16*   P1    = xb;                       // [0,16M)  partial O half0 (over dead xb)
  u16*   P2    = (u16*)(ws + 62914560);    // [60,76M) partial O half1
  float* l1    = (float*)(ws + 79691776);  // 512KB
  float* l2    = (float*)(ws + 80216064);  // 512KB
  u16*   attnOut = qTp;                    // combine writes over dead qTp

  // all fp32 -> bf16 converts in one launch
  k_f2b_all<<<dim3(18432), 256, 0, stream>>>(x, Wq, Wk, Wv, Wo, xb, wqkvb, wob);

  // fused QKV projection + RoPE + V-transpose scatter
  k_gemm_qkv<<<dim3(24, 32), 256, 0, stream>>>(xb, wqkvb, qTp, kTp, vTp);

  // split-K flash attention: 2048 half-jobs, longest-first (HW backfill)
  k_attn<<<dim3(2048), 256, 0, stream>>>(qTp, kTp, vTp, P1, P2, l1, l2);

  // combine partials + normalize
  k_combine<<<dim3(8192), 256, 0, stream>>>(P1, P2, l1, l2, attnOut);

  // output projection: (4096 x 2048) * (2048 x 2048)^T -> fp32 d_out
  k_gemm_bt<<<dim3(16, 32), 256, 0, stream>>>(attnOut, wob, (float*)d_out, 2048);
}